// Round 2
// baseline (4230.255 us; speedup 1.0000x reference)
//
#include <hip/hip_runtime.h>
#include <hip/hip_bf16.h>

#define N_NODES 100000
#define E_GRAPH 300000
#define E_CAND  200000
#define HID     256
#define RPB     16   // rows per block in node GEMMs
#define EB      16   // edges per block in decode

// ---------------- workspace layout (floats) ----------------
// z:    N*HID        (node features; also reused as agg target)
// h:    N*HID        (z @ conv_W[l])
// deg:  N (int)      (in-degree counts on col)
// dinv: N            (rsqrt degree)
// dtab: 100*HID      (degree_emb @ proj_W[256:272,:])
// htab: 4*100*HID    (heur_emb[i] @ dec_W1[256+16i:256+16(i+1),:])
static const size_t OFF_Z    = 0;
static const size_t OFF_H    = (size_t)N_NODES * HID;
static const size_t OFF_DEG  = 2 * (size_t)N_NODES * HID;
static const size_t OFF_DINV = OFF_DEG + N_NODES;
static const size_t OFF_DTAB = OFF_DINV + N_NODES;
static const size_t OFF_HTAB = OFF_DTAB + 100 * HID;

__global__ void count_deg_k(const int* __restrict__ col, int* __restrict__ deg) {
    int i = blockIdx.x * 256 + threadIdx.x;
    if (i < E_GRAPH) atomicAdd(&deg[col[i]], 1);
}

__global__ void dinv_k(const int* __restrict__ deg, float* __restrict__ dinv) {
    int i = blockIdx.x * 256 + threadIdx.x;
    if (i < N_NODES) {
        int d = deg[i];
        dinv[i] = d > 0 ? 1.0f / sqrtf((float)d) : 0.0f;
    }
}

// dtab[b][j] = sum_t degree_emb[b][t] * proj_W[(256+t)][j]
__global__ void dtab_k(const float* __restrict__ demb, const float* __restrict__ projW,
                       float* __restrict__ dtab) {
    int b = blockIdx.x, j = threadIdx.x;
    float acc = 0.f;
#pragma unroll
    for (int t = 0; t < 16; ++t)
        acc = fmaf(demb[b * 16 + t], projW[(256 + t) * HID + j], acc);
    dtab[b * HID + j] = acc;
}

// htab[(i*100+v)][j] = sum_t heur_emb[i][v][t] * dec_W1[(256+16i+t)][j]
__global__ void htab_k(const float* __restrict__ hemb, const float* __restrict__ W1,
                       float* __restrict__ htab) {
    int b = blockIdx.x;           // i*100 + v
    int i = b / 100, j = threadIdx.x;
    float acc = 0.f;
#pragma unroll
    for (int t = 0; t < 16; ++t)
        acc = fmaf(hemb[b * 16 + t], W1[(256 + i * 16 + t) * HID + j], acc);
    htab[b * HID + j] = acc;
}

// z[i][:] = node_emb[i] @ proj_W[0:256] + dtab[bin(deg_i)] + proj_b
__global__ __launch_bounds__(256) void proj_k(const float* __restrict__ ne,
        const float* __restrict__ W, const float* __restrict__ bvec,
        const float* __restrict__ dtab, const int* __restrict__ degs,
        float* __restrict__ z) {
    __shared__ __align__(16) float a_s[RPB][HID];
    __shared__ int bin_s[RPB];
    int tid = threadIdx.x;
    int row0 = blockIdx.x * RPB;
    for (int idx = tid; idx < RPB * HID; idx += 256)
        a_s[idx >> 8][idx & 255] = ne[(size_t)row0 * HID + idx];
    if (tid < RPB) {
        int b = (int)log1pf((float)degs[row0 + tid]);
        bin_s[tid] = b < 0 ? 0 : (b > 99 ? 99 : b);
    }
    __syncthreads();
    int j = tid;
    float acc[RPB];
#pragma unroll
    for (int r = 0; r < RPB; ++r)
        acc[r] = bvec[j] + dtab[bin_s[r] * HID + j];
    for (int k = 0; k < HID; k += 4) {
        float w0 = W[(k + 0) * HID + j], w1 = W[(k + 1) * HID + j];
        float w2 = W[(k + 2) * HID + j], w3 = W[(k + 3) * HID + j];
#pragma unroll
        for (int r = 0; r < RPB; ++r) {
            float4 av = *(const float4*)&a_s[r][k];
            acc[r] = fmaf(av.x, w0, fmaf(av.y, w1, fmaf(av.z, w2, fmaf(av.w, w3, acc[r]))));
        }
    }
#pragma unroll
    for (int r = 0; r < RPB; ++r)
        z[(size_t)(row0 + r) * HID + j] = acc[r];
}

// h = z @ conv_W[l]
__global__ __launch_bounds__(256) void gemm_conv_k(const float* __restrict__ zin,
        const float* __restrict__ W, float* __restrict__ hout) {
    __shared__ __align__(16) float a_s[RPB][HID];
    int tid = threadIdx.x;
    int row0 = blockIdx.x * RPB;
    for (int idx = tid; idx < RPB * HID; idx += 256)
        a_s[idx >> 8][idx & 255] = zin[(size_t)row0 * HID + idx];
    __syncthreads();
    int j = tid;
    float acc[RPB];
#pragma unroll
    for (int r = 0; r < RPB; ++r) acc[r] = 0.f;
    for (int k = 0; k < HID; k += 4) {
        float w0 = W[(k + 0) * HID + j], w1 = W[(k + 1) * HID + j];
        float w2 = W[(k + 2) * HID + j], w3 = W[(k + 3) * HID + j];
#pragma unroll
        for (int r = 0; r < RPB; ++r) {
            float4 av = *(const float4*)&a_s[r][k];
            acc[r] = fmaf(av.x, w0, fmaf(av.y, w1, fmaf(av.z, w2, fmaf(av.w, w3, acc[r]))));
        }
    }
#pragma unroll
    for (int r = 0; r < RPB; ++r)
        hout[(size_t)(row0 + r) * HID + j] = acc[r];
}

// agg[c] += h[r] * dinv[r]*dinv[c]   (one wave per edge, 4 floats per lane)
__global__ __launch_bounds__(256) void scatter_k(const int* __restrict__ ei,
        const float* __restrict__ dinv, const float* __restrict__ h,
        float* __restrict__ agg) {
    int gid = blockIdx.x * 256 + threadIdx.x;
    int e = gid >> 6, lane = gid & 63;
    if (e >= E_GRAPH) return;
    int r = ei[e], c = ei[E_GRAPH + e];
    float nv = dinv[r] * dinv[c];
    float4 hv = *(const float4*)&h[(size_t)r * HID + lane * 4];
    float* dst = &agg[(size_t)c * HID + lane * 4];
    atomicAdd(dst + 0, hv.x * nv);
    atomicAdd(dst + 1, hv.y * nv);
    atomicAdd(dst + 2, hv.z * nv);
    atomicAdd(dst + 3, hv.w * nv);
}

__global__ void bias_relu_k(float* __restrict__ z, const float* __restrict__ b) {
    size_t gid = (size_t)blockIdx.x * 256 + threadIdx.x;
    size_t base = gid * 4;
    int j = (int)(base & (HID - 1));
    float4 v = *(float4*)&z[base];
    v.x = fmaxf(v.x + b[j + 0], 0.f);
    v.y = fmaxf(v.y + b[j + 1], 0.f);
    v.z = fmaxf(v.z + b[j + 2], 0.f);
    v.w = fmaxf(v.w + b[j + 3], 0.f);
    *(float4*)&z[base] = v;
}

// fused decoder: structural gather -> W1(+folded heur tables) -> W2 -> W3
__global__ __launch_bounds__(256) void decode_k(const float* __restrict__ z,
        const int* __restrict__ edges, const int* __restrict__ heur,
        const float* __restrict__ htab,
        const float* __restrict__ W1, const float* __restrict__ b1,
        const float* __restrict__ W2, const float* __restrict__ b2,
        const float* __restrict__ W3, const float* __restrict__ b3,
        float* __restrict__ out) {
    __shared__ __align__(16) float s_s[EB][HID];
    __shared__ __align__(16) float x1_s[EB][HID];
    __shared__ __align__(16) float x2_s[EB][64];
    __shared__ int hv_s[EB][4];
    int tid = threadIdx.x;
    int e0 = blockIdx.x * EB;
    for (int idx = tid; idx < EB * HID; idx += 256) {
        int e = idx >> 8, k = idx & 255;
        int a = edges[(e0 + e) * 2], b = edges[(e0 + e) * 2 + 1];
        s_s[e][k] = z[(size_t)a * HID + k] * z[(size_t)b * HID + k];
    }
    if (tid < EB * 4) hv_s[tid >> 2][tid & 3] = heur[(e0 + (tid >> 2)) * 4 + (tid & 3)];
    __syncthreads();
    int j = tid;
    float acc[EB];
#pragma unroll
    for (int e = 0; e < EB; ++e) {
        acc[e] = b1[j]
               + htab[(0 * 100 + hv_s[e][0]) * HID + j]
               + htab[(1 * 100 + hv_s[e][1]) * HID + j]
               + htab[(2 * 100 + hv_s[e][2]) * HID + j]
               + htab[(3 * 100 + hv_s[e][3]) * HID + j];
    }
    for (int k = 0; k < HID; k += 4) {
        float w0 = W1[(k + 0) * HID + j], w1 = W1[(k + 1) * HID + j];
        float w2 = W1[(k + 2) * HID + j], w3 = W1[(k + 3) * HID + j];
#pragma unroll
        for (int e = 0; e < EB; ++e) {
            float4 av = *(const float4*)&s_s[e][k];
            acc[e] = fmaf(av.x, w0, fmaf(av.y, w1, fmaf(av.z, w2, fmaf(av.w, w3, acc[e]))));
        }
    }
#pragma unroll
    for (int e = 0; e < EB; ++e) x1_s[e][j] = fmaxf(acc[e], 0.f);
    __syncthreads();
    {
        int f = tid & 63, es = tid >> 6;   // 64 cols x 4 edge-strips
        float a2[4];
#pragma unroll
        for (int q = 0; q < 4; ++q) a2[q] = b2[f];
        for (int k = 0; k < HID; k += 4) {
            float w0 = W2[(k + 0) * 64 + f], w1 = W2[(k + 1) * 64 + f];
            float w2v = W2[(k + 2) * 64 + f], w3v = W2[(k + 3) * 64 + f];
#pragma unroll
            for (int q = 0; q < 4; ++q) {
                float4 av = *(const float4*)&x1_s[es * 4 + q][k];
                a2[q] = fmaf(av.x, w0, fmaf(av.y, w1, fmaf(av.z, w2v, fmaf(av.w, w3v, a2[q]))));
            }
        }
#pragma unroll
        for (int q = 0; q < 4; ++q) x2_s[es * 4 + q][f] = fmaxf(a2[q], 0.f);
    }
    __syncthreads();
    if (tid < EB) {
        float a3 = b3[0];
#pragma unroll
        for (int k = 0; k < 64; ++k) a3 = fmaf(x2_s[tid][k], W3[k], a3);
        out[e0 + tid] = a3;
    }
}

extern "C" void kernel_launch(void* const* d_in, const int* in_sizes, int n_in,
                              void* d_out, int out_size, void* d_ws, size_t ws_size,
                              hipStream_t stream) {
    (void)in_sizes; (void)n_in; (void)out_size; (void)ws_size;
    const int*   edge_index = (const int*)d_in[0];
    const int*   pos_edge   = (const int*)d_in[1];
    const int*   neg_edge   = (const int*)d_in[2];
    const int*   pos_h      = (const int*)d_in[3];
    const int*   neg_h      = (const int*)d_in[4];
    const int*   degrees    = (const int*)d_in[5];
    const float* node_emb   = (const float*)d_in[6];
    const float* degree_emb = (const float*)d_in[7];
    const float* proj_W     = (const float*)d_in[8];
    const float* proj_b     = (const float*)d_in[9];
    const float* conv_W     = (const float*)d_in[10];
    const float* conv_b     = (const float*)d_in[11];
    const float* heur_emb   = (const float*)d_in[12];
    const float* W1         = (const float*)d_in[13];
    const float* b1         = (const float*)d_in[14];
    const float* W2         = (const float*)d_in[15];
    const float* b2         = (const float*)d_in[16];
    const float* W3         = (const float*)d_in[17];
    const float* b3         = (const float*)d_in[18];
    float* out = (float*)d_out;
    float* ws  = (float*)d_ws;

    float* z    = ws + OFF_Z;
    float* h    = ws + OFF_H;
    int*   deg  = (int*)(ws + OFF_DEG);
    float* dinv = ws + OFF_DINV;
    float* dtab = ws + OFF_DTAB;
    float* htab = ws + OFF_HTAB;

    hipMemsetAsync(deg, 0, N_NODES * sizeof(int), stream);
    count_deg_k<<<(E_GRAPH + 255) / 256, 256, 0, stream>>>(edge_index + E_GRAPH, deg);
    dinv_k<<<(N_NODES + 255) / 256, 256, 0, stream>>>(deg, dinv);
    dtab_k<<<100, 256, 0, stream>>>(degree_emb, proj_W, dtab);
    htab_k<<<400, 256, 0, stream>>>(heur_emb, W1, htab);

    proj_k<<<N_NODES / RPB, 256, 0, stream>>>(node_emb, proj_W, proj_b, dtab, degrees, z);

    for (int l = 0; l < 2; ++l) {
        gemm_conv_k<<<N_NODES / RPB, 256, 0, stream>>>(z, conv_W + l * HID * HID, h);
        hipMemsetAsync(z, 0, (size_t)N_NODES * HID * sizeof(float), stream);
        scatter_k<<<E_GRAPH * 64 / 256, 256, 0, stream>>>(edge_index, dinv, h, z);
        bias_relu_k<<<N_NODES * HID / 4 / 256, 256, 0, stream>>>(z, conv_b + l * HID);
    }

    decode_k<<<E_CAND / EB, 256, 0, stream>>>(z, pos_edge, pos_h, htab,
                                              W1, b1, W2, b2, W3, b3, out);
    decode_k<<<E_CAND / EB, 256, 0, stream>>>(z, neg_edge, neg_h, htab,
                                              W1, b1, W2, b2, W3, b3, out + E_CAND);
}

// Round 3
// 2249.379 us; speedup vs baseline: 1.8806x; 1.8806x over previous
//
#include <hip/hip_runtime.h>
#include <hip/hip_bf16.h>

#define N_NODES 100000
#define E_GRAPH 300000
#define E_CAND  200000
#define HID     256
#define RPB     16   // rows per block in node GEMMs
#define EB      16   // edges per block in decode
#define NB_SCAN ((N_NODES + 255) / 256)   // 391

// ---------------- workspace layout (floats) ----------------
static const size_t OFF_Z    = 0;
static const size_t OFF_H    = (size_t)N_NODES * HID;
static const size_t OFF_DEG  = 2 * (size_t)N_NODES * HID;          // N ints
static const size_t OFF_DINV = OFF_DEG + N_NODES;                  // N floats
static const size_t OFF_DTAB = OFF_DINV + N_NODES;                 // 100*HID
static const size_t OFF_HTAB = OFF_DTAB + 100 * HID;               // 4*100*HID
static const size_t OFF_OFFS = OFF_HTAB + 4 * 100 * HID;           // N+1 ints
static const size_t OFF_BSUM = OFF_OFFS + N_NODES + 1;             // 512 ints
static const size_t OFF_CURS = OFF_BSUM + 512;                     // N ints
static const size_t OFF_CSRC = OFF_CURS + N_NODES;                 // E ints
static const size_t OFF_CNRM = OFF_CSRC + E_GRAPH;                 // E floats

__global__ void count_deg_k(const int* __restrict__ col, int* __restrict__ deg) {
    int i = blockIdx.x * 256 + threadIdx.x;
    if (i < E_GRAPH) atomicAdd(&deg[col[i]], 1);
}

__global__ void dinv_k(const int* __restrict__ deg, float* __restrict__ dinv) {
    int i = blockIdx.x * 256 + threadIdx.x;
    if (i < N_NODES) {
        int d = deg[i];
        dinv[i] = d > 0 ? 1.0f / sqrtf((float)d) : 0.0f;
    }
}

// ---- 3-kernel exclusive scan of deg -> offs ----
__global__ void scan_block_k(const int* __restrict__ deg, int* __restrict__ offs,
                             int* __restrict__ bsum) {
    __shared__ int s[256];
    int tid = threadIdx.x, i = blockIdx.x * 256 + tid;
    int v = (i < N_NODES) ? deg[i] : 0;
    s[tid] = v;
    __syncthreads();
    for (int off = 1; off < 256; off <<= 1) {
        int t = (tid >= off) ? s[tid - off] : 0;
        __syncthreads();
        s[tid] += t;
        __syncthreads();
    }
    if (i < N_NODES) offs[i] = s[tid] - v;          // exclusive within block
    if (tid == 255) bsum[blockIdx.x] = s[255];
}

__global__ void scan_bsum_k(int* __restrict__ bsum, int* __restrict__ offs) {
    __shared__ int s[512];
    int tid = threadIdx.x;
    int v = (tid < NB_SCAN) ? bsum[tid] : 0;
    s[tid] = v;
    __syncthreads();
    for (int off = 1; off < 512; off <<= 1) {
        int t = (tid >= off) ? s[tid - off] : 0;
        __syncthreads();
        s[tid] += t;
        __syncthreads();
    }
    if (tid < NB_SCAN) bsum[tid] = s[tid] - v;      // exclusive
    if (tid == 0) offs[N_NODES] = E_GRAPH;
}

__global__ void add_bsum_k(int* __restrict__ offs, const int* __restrict__ bsum,
                           int* __restrict__ cursor) {
    int i = blockIdx.x * 256 + threadIdx.x;
    if (i < N_NODES) {
        int o = offs[i] + bsum[i >> 8];
        offs[i] = o;
        cursor[i] = o;
    }
}

// bucket edges by destination; store src index + edge norm
__global__ void bucket_k(const int* __restrict__ ei, const float* __restrict__ dinv,
                         int* __restrict__ cursor, int* __restrict__ csr_src,
                         float* __restrict__ csr_norm) {
    int e = blockIdx.x * 256 + threadIdx.x;
    if (e < E_GRAPH) {
        int r = ei[e], c = ei[E_GRAPH + e];
        int pos = atomicAdd(&cursor[c], 1);
        csr_src[pos] = r;
        csr_norm[pos] = dinv[r] * dinv[c];
    }
}

// dtab[b][j] = sum_t degree_emb[b][t] * proj_W[(256+t)][j]
__global__ void dtab_k(const float* __restrict__ demb, const float* __restrict__ projW,
                       float* __restrict__ dtab) {
    int b = blockIdx.x, j = threadIdx.x;
    float acc = 0.f;
#pragma unroll
    for (int t = 0; t < 16; ++t)
        acc = fmaf(demb[b * 16 + t], projW[(256 + t) * HID + j], acc);
    dtab[b * HID + j] = acc;
}

// htab[(i*100+v)][j] = sum_t heur_emb[i][v][t] * dec_W1[(256+16i+t)][j]
__global__ void htab_k(const float* __restrict__ hemb, const float* __restrict__ W1,
                       float* __restrict__ htab) {
    int b = blockIdx.x;           // i*100 + v
    int i = b / 100, j = threadIdx.x;
    float acc = 0.f;
#pragma unroll
    for (int t = 0; t < 16; ++t)
        acc = fmaf(hemb[b * 16 + t], W1[(256 + i * 16 + t) * HID + j], acc);
    htab[b * HID + j] = acc;
}

// z[i][:] = node_emb[i] @ proj_W[0:256] + dtab[bin(deg_i)] + proj_b
__global__ __launch_bounds__(256) void proj_k(const float* __restrict__ ne,
        const float* __restrict__ W, const float* __restrict__ bvec,
        const float* __restrict__ dtab, const int* __restrict__ degs,
        float* __restrict__ z) {
    __shared__ __align__(16) float a_s[RPB][HID];
    __shared__ int bin_s[RPB];
    int tid = threadIdx.x;
    int row0 = blockIdx.x * RPB;
    for (int idx = tid; idx < RPB * HID; idx += 256)
        a_s[idx >> 8][idx & 255] = ne[(size_t)row0 * HID + idx];
    if (tid < RPB) {
        int b = (int)log1pf((float)degs[row0 + tid]);
        bin_s[tid] = b < 0 ? 0 : (b > 99 ? 99 : b);
    }
    __syncthreads();
    int j = tid;
    float acc[RPB];
#pragma unroll
    for (int r = 0; r < RPB; ++r)
        acc[r] = bvec[j] + dtab[bin_s[r] * HID + j];
    for (int k = 0; k < HID; k += 4) {
        float w0 = W[(k + 0) * HID + j], w1 = W[(k + 1) * HID + j];
        float w2 = W[(k + 2) * HID + j], w3 = W[(k + 3) * HID + j];
#pragma unroll
        for (int r = 0; r < RPB; ++r) {
            float4 av = *(const float4*)&a_s[r][k];
            acc[r] = fmaf(av.x, w0, fmaf(av.y, w1, fmaf(av.z, w2, fmaf(av.w, w3, acc[r]))));
        }
    }
#pragma unroll
    for (int r = 0; r < RPB; ++r)
        z[(size_t)(row0 + r) * HID + j] = acc[r];
}

// h = z @ conv_W[l]
__global__ __launch_bounds__(256) void gemm_conv_k(const float* __restrict__ zin,
        const float* __restrict__ W, float* __restrict__ hout) {
    __shared__ __align__(16) float a_s[RPB][HID];
    int tid = threadIdx.x;
    int row0 = blockIdx.x * RPB;
    for (int idx = tid; idx < RPB * HID; idx += 256)
        a_s[idx >> 8][idx & 255] = zin[(size_t)row0 * HID + idx];
    __syncthreads();
    int j = tid;
    float acc[RPB];
#pragma unroll
    for (int r = 0; r < RPB; ++r) acc[r] = 0.f;
    for (int k = 0; k < HID; k += 4) {
        float w0 = W[(k + 0) * HID + j], w1 = W[(k + 1) * HID + j];
        float w2 = W[(k + 2) * HID + j], w3 = W[(k + 3) * HID + j];
#pragma unroll
        for (int r = 0; r < RPB; ++r) {
            float4 av = *(const float4*)&a_s[r][k];
            acc[r] = fmaf(av.x, w0, fmaf(av.y, w1, fmaf(av.z, w2, fmaf(av.w, w3, acc[r]))));
        }
    }
#pragma unroll
    for (int r = 0; r < RPB; ++r)
        hout[(size_t)(row0 + r) * HID + j] = acc[r];
}

// CSR gather: z[c] = relu( sum_{e in bucket(c)} h[src_e]*norm_e + bias )
// one wave per dest node, 4 floats per lane; fuses bias+relu (no z memset needed)
__global__ __launch_bounds__(256) void agg_k(const int* __restrict__ offs,
        const int* __restrict__ csr_src, const float* __restrict__ csr_norm,
        const float* __restrict__ h, const float* __restrict__ bias,
        float* __restrict__ z) {
    int node = blockIdx.x * 4 + (threadIdx.x >> 6);
    int lane = threadIdx.x & 63;
    int s = offs[node], e = offs[node + 1];
    float4 acc = make_float4(0.f, 0.f, 0.f, 0.f);
    for (int i = s; i < e; ++i) {
        int r = csr_src[i];
        float nv = csr_norm[i];
        float4 hv = *(const float4*)&h[(size_t)r * HID + lane * 4];
        acc.x = fmaf(hv.x, nv, acc.x);
        acc.y = fmaf(hv.y, nv, acc.y);
        acc.z = fmaf(hv.z, nv, acc.z);
        acc.w = fmaf(hv.w, nv, acc.w);
    }
    float4 bv = *(const float4*)&bias[lane * 4];
    acc.x = fmaxf(acc.x + bv.x, 0.f);
    acc.y = fmaxf(acc.y + bv.y, 0.f);
    acc.z = fmaxf(acc.z + bv.z, 0.f);
    acc.w = fmaxf(acc.w + bv.w, 0.f);
    *(float4*)&z[(size_t)node * HID + lane * 4] = acc;
}

// fused decoder: structural gather -> W1(+folded heur tables) -> W2 -> W3
__global__ __launch_bounds__(256) void decode_k(const float* __restrict__ z,
        const int* __restrict__ edges, const int* __restrict__ heur,
        const float* __restrict__ htab,
        const float* __restrict__ W1, const float* __restrict__ b1,
        const float* __restrict__ W2, const float* __restrict__ b2,
        const float* __restrict__ W3, const float* __restrict__ b3,
        float* __restrict__ out) {
    __shared__ __align__(16) float s_s[EB][HID];
    __shared__ __align__(16) float x1_s[EB][HID];
    __shared__ __align__(16) float x2_s[EB][64];
    __shared__ int hv_s[EB][4];
    int tid = threadIdx.x;
    int e0 = blockIdx.x * EB;
    for (int idx = tid; idx < EB * HID; idx += 256) {
        int e = idx >> 8, k = idx & 255;
        int a = edges[(e0 + e) * 2], b = edges[(e0 + e) * 2 + 1];
        s_s[e][k] = z[(size_t)a * HID + k] * z[(size_t)b * HID + k];
    }
    if (tid < EB * 4) hv_s[tid >> 2][tid & 3] = heur[(e0 + (tid >> 2)) * 4 + (tid & 3)];
    __syncthreads();
    int j = tid;
    float acc[EB];
#pragma unroll
    for (int e = 0; e < EB; ++e) {
        acc[e] = b1[j]
               + htab[(0 * 100 + hv_s[e][0]) * HID + j]
               + htab[(1 * 100 + hv_s[e][1]) * HID + j]
               + htab[(2 * 100 + hv_s[e][2]) * HID + j]
               + htab[(3 * 100 + hv_s[e][3]) * HID + j];
    }
    for (int k = 0; k < HID; k += 4) {
        float w0 = W1[(k + 0) * HID + j], w1 = W1[(k + 1) * HID + j];
        float w2 = W1[(k + 2) * HID + j], w3 = W1[(k + 3) * HID + j];
#pragma unroll
        for (int e = 0; e < EB; ++e) {
            float4 av = *(const float4*)&s_s[e][k];
            acc[e] = fmaf(av.x, w0, fmaf(av.y, w1, fmaf(av.z, w2, fmaf(av.w, w3, acc[e]))));
        }
    }
#pragma unroll
    for (int e = 0; e < EB; ++e) x1_s[e][j] = fmaxf(acc[e], 0.f);
    __syncthreads();
    {
        int f = tid & 63, es = tid >> 6;   // 64 cols x 4 edge-strips
        float a2[4];
#pragma unroll
        for (int q = 0; q < 4; ++q) a2[q] = b2[f];
        for (int k = 0; k < HID; k += 4) {
            float w0 = W2[(k + 0) * 64 + f], w1 = W2[(k + 1) * 64 + f];
            float w2v = W2[(k + 2) * 64 + f], w3v = W2[(k + 3) * 64 + f];
#pragma unroll
            for (int q = 0; q < 4; ++q) {
                float4 av = *(const float4*)&x1_s[es * 4 + q][k];
                a2[q] = fmaf(av.x, w0, fmaf(av.y, w1, fmaf(av.z, w2v, fmaf(av.w, w3v, a2[q]))));
            }
        }
#pragma unroll
        for (int q = 0; q < 4; ++q) x2_s[es * 4 + q][f] = fmaxf(a2[q], 0.f);
    }
    __syncthreads();
    if (tid < EB) {
        float a3 = b3[0];
#pragma unroll
        for (int k = 0; k < 64; ++k) a3 = fmaf(x2_s[tid][k], W3[k], a3);
        out[e0 + tid] = a3;
    }
}

extern "C" void kernel_launch(void* const* d_in, const int* in_sizes, int n_in,
                              void* d_out, int out_size, void* d_ws, size_t ws_size,
                              hipStream_t stream) {
    (void)in_sizes; (void)n_in; (void)out_size; (void)ws_size;
    const int*   edge_index = (const int*)d_in[0];
    const int*   pos_edge   = (const int*)d_in[1];
    const int*   neg_edge   = (const int*)d_in[2];
    const int*   pos_h      = (const int*)d_in[3];
    const int*   neg_h      = (const int*)d_in[4];
    const int*   degrees    = (const int*)d_in[5];
    const float* node_emb   = (const float*)d_in[6];
    const float* degree_emb = (const float*)d_in[7];
    const float* proj_W     = (const float*)d_in[8];
    const float* proj_b     = (const float*)d_in[9];
    const float* conv_W     = (const float*)d_in[10];
    const float* conv_b     = (const float*)d_in[11];
    const float* heur_emb   = (const float*)d_in[12];
    const float* W1         = (const float*)d_in[13];
    const float* b1         = (const float*)d_in[14];
    const float* W2         = (const float*)d_in[15];
    const float* b2         = (const float*)d_in[16];
    const float* W3         = (const float*)d_in[17];
    const float* b3         = (const float*)d_in[18];
    float* out = (float*)d_out;
    float* ws  = (float*)d_ws;

    float* z        = ws + OFF_Z;
    float* h        = ws + OFF_H;
    int*   deg      = (int*)(ws + OFF_DEG);
    float* dinv     = ws + OFF_DINV;
    float* dtab     = ws + OFF_DTAB;
    float* htab     = ws + OFF_HTAB;
    int*   offs     = (int*)(ws + OFF_OFFS);
    int*   bsum     = (int*)(ws + OFF_BSUM);
    int*   cursor   = (int*)(ws + OFF_CURS);
    int*   csr_src  = (int*)(ws + OFF_CSRC);
    float* csr_norm = ws + OFF_CNRM;

    hipMemsetAsync(deg, 0, N_NODES * sizeof(int), stream);
    count_deg_k<<<(E_GRAPH + 255) / 256, 256, 0, stream>>>(edge_index + E_GRAPH, deg);
    dinv_k<<<(N_NODES + 255) / 256, 256, 0, stream>>>(deg, dinv);

    // build CSR (by destination) once; reused by both conv layers
    scan_block_k<<<NB_SCAN, 256, 0, stream>>>(deg, offs, bsum);
    scan_bsum_k<<<1, 512, 0, stream>>>(bsum, offs);
    add_bsum_k<<<NB_SCAN, 256, 0, stream>>>(offs, bsum, cursor);
    bucket_k<<<(E_GRAPH + 255) / 256, 256, 0, stream>>>(edge_index, dinv, cursor,
                                                        csr_src, csr_norm);

    dtab_k<<<100, 256, 0, stream>>>(degree_emb, proj_W, dtab);
    htab_k<<<400, 256, 0, stream>>>(heur_emb, W1, htab);

    proj_k<<<N_NODES / RPB, 256, 0, stream>>>(node_emb, proj_W, proj_b, dtab, degrees, z);

    for (int l = 0; l < 2; ++l) {
        gemm_conv_k<<<N_NODES / RPB, 256, 0, stream>>>(z, conv_W + l * HID * HID, h);
        agg_k<<<N_NODES / 4, 256, 0, stream>>>(offs, csr_src, csr_norm, h,
                                               conv_b + l * HID, z);
    }

    decode_k<<<E_CAND / EB, 256, 0, stream>>>(z, pos_edge, pos_h, htab,
                                              W1, b1, W2, b2, W3, b3, out);
    decode_k<<<E_CAND / EB, 256, 0, stream>>>(z, neg_edge, neg_h, htab,
                                              W1, b1, W2, b2, W3, b3, out + E_CAND);
}

// Round 5
// 1660.628 us; speedup vs baseline: 2.5474x; 1.3545x over previous
//
#include <hip/hip_runtime.h>
#include <hip/hip_bf16.h>

#define N_NODES 100000
#define E_GRAPH 300000
#define E_CAND  200000
#define HID     256
#define RPB     16   // rows per block in node GEMMs
#define NB_SCAN ((N_NODES + 255) / 256)   // 391
#define SPAD    264  // padded bf16 LDS row (528 B = 4 banks offset/row -> 2-way, free)

typedef __attribute__((ext_vector_type(8))) short bf16x8;
typedef __attribute__((ext_vector_type(4))) float f32x4;

// ---------------- workspace layout (float units) ----------------
static const size_t OFF_Z    = 0;
static const size_t OFF_H    = (size_t)N_NODES * HID;
static const size_t OFF_DEG  = 2 * (size_t)N_NODES * HID;          // N ints
static const size_t OFF_DINV = OFF_DEG + N_NODES;                  // N floats
static const size_t OFF_DTAB = OFF_DINV + N_NODES;                 // 100*HID
static const size_t OFF_HTAB = OFF_DTAB + 100 * HID;               // 4*100*HID
static const size_t OFF_OFFS = OFF_HTAB + 4 * 100 * HID;           // N+1 ints
static const size_t OFF_BSUM = OFF_OFFS + N_NODES + 1;             // 512 ints
static const size_t OFF_CURS = OFF_BSUM + 512;                     // N ints
static const size_t OFF_CSRC = OFF_CURS + N_NODES;                 // E ints
static const size_t OFF_CNRM = OFF_CSRC + E_GRAPH;                 // E floats
static const size_t OFF_W1T  = OFF_CNRM + E_GRAPH;                 // 256*256 bf16 = 32768 f
static const size_t OFF_W2T  = OFF_W1T + 32768;                    // 64*256 bf16 = 8192 f

__device__ inline unsigned short f2bf(float f) {
    __hip_bfloat16 h = __float2bfloat16(f);
    return *reinterpret_cast<unsigned short*>(&h);
}

__global__ void count_deg_k(const int* __restrict__ col, int* __restrict__ deg) {
    int i = blockIdx.x * 256 + threadIdx.x;
    if (i < E_GRAPH) atomicAdd(&deg[col[i]], 1);
}

__global__ void dinv_k(const int* __restrict__ deg, float* __restrict__ dinv) {
    int i = blockIdx.x * 256 + threadIdx.x;
    if (i < N_NODES) {
        int d = deg[i];
        dinv[i] = d > 0 ? 1.0f / sqrtf((float)d) : 0.0f;
    }
}

// ---- 3-kernel exclusive scan of deg -> offs ----
__global__ void scan_block_k(const int* __restrict__ deg, int* __restrict__ offs,
                             int* __restrict__ bsum) {
    __shared__ int s[256];
    int tid = threadIdx.x, i = blockIdx.x * 256 + tid;
    int v = (i < N_NODES) ? deg[i] : 0;
    s[tid] = v;
    __syncthreads();
    for (int off = 1; off < 256; off <<= 1) {
        int t = (tid >= off) ? s[tid - off] : 0;
        __syncthreads();
        s[tid] += t;
        __syncthreads();
    }
    if (i < N_NODES) offs[i] = s[tid] - v;
    if (tid == 255) bsum[blockIdx.x] = s[255];
}

__global__ void scan_bsum_k(int* __restrict__ bsum, int* __restrict__ offs) {
    __shared__ int s[512];
    int tid = threadIdx.x;
    int v = (tid < NB_SCAN) ? bsum[tid] : 0;
    s[tid] = v;
    __syncthreads();
    for (int off = 1; off < 512; off <<= 1) {
        int t = (tid >= off) ? s[tid - off] : 0;
        __syncthreads();
        s[tid] += t;
        __syncthreads();
    }
    if (tid < NB_SCAN) bsum[tid] = s[tid] - v;
    if (tid == 0) offs[N_NODES] = E_GRAPH;
}

__global__ void add_bsum_k(int* __restrict__ offs, const int* __restrict__ bsum,
                           int* __restrict__ cursor) {
    int i = blockIdx.x * 256 + threadIdx.x;
    if (i < N_NODES) {
        int o = offs[i] + bsum[i >> 8];
        offs[i] = o;
        cursor[i] = o;
    }
}

__global__ void bucket_k(const int* __restrict__ ei, const float* __restrict__ dinv,
                         int* __restrict__ cursor, int* __restrict__ csr_src,
                         float* __restrict__ csr_norm) {
    int e = blockIdx.x * 256 + threadIdx.x;
    if (e < E_GRAPH) {
        int r = ei[e], c = ei[E_GRAPH + e];
        int pos = atomicAdd(&cursor[c], 1);
        csr_src[pos] = r;
        csr_norm[pos] = dinv[r] * dinv[c];
    }
}

__global__ void dtab_k(const float* __restrict__ demb, const float* __restrict__ projW,
                       float* __restrict__ dtab) {
    int b = blockIdx.x, j = threadIdx.x;
    float acc = 0.f;
#pragma unroll
    for (int t = 0; t < 16; ++t)
        acc = fmaf(demb[b * 16 + t], projW[(256 + t) * HID + j], acc);
    dtab[b * HID + j] = acc;
}

__global__ void htab_k(const float* __restrict__ hemb, const float* __restrict__ W1,
                       float* __restrict__ htab) {
    int b = blockIdx.x;           // i*100 + v
    int i = b / 100, j = threadIdx.x;
    float acc = 0.f;
#pragma unroll
    for (int t = 0; t < 16; ++t)
        acc = fmaf(hemb[b * 16 + t], W1[(256 + i * 16 + t) * HID + j], acc);
    htab[b * HID + j] = acc;
}

// transpose+cast dec_W1[0:256][0:256] -> W1T[n][k] bf16
__global__ void w1t_k(const float* __restrict__ W1, unsigned short* __restrict__ W1T) {
    int n = blockIdx.x, k = threadIdx.x;
    W1T[n * 256 + k] = f2bf(W1[k * 256 + n]);
}

// transpose+cast dec_W2[256][64] -> W2T[n][k] bf16
__global__ void w2t_k(const float* __restrict__ W2, unsigned short* __restrict__ W2T) {
    int n = blockIdx.x, k = threadIdx.x;
    W2T[n * 256 + k] = f2bf(W2[k * 64 + n]);
}

// z[i][:] = node_emb[i] @ proj_W[0:256] + dtab[bin(deg_i)] + proj_b   (fp32)
__global__ __launch_bounds__(256) void proj_k(const float* __restrict__ ne,
        const float* __restrict__ W, const float* __restrict__ bvec,
        const float* __restrict__ dtab, const int* __restrict__ degs,
        float* __restrict__ z) {
    __shared__ __align__(16) float a_s[RPB][HID];
    __shared__ int bin_s[RPB];
    int tid = threadIdx.x;
    int row0 = blockIdx.x * RPB;
    for (int idx = tid; idx < RPB * HID; idx += 256)
        a_s[idx >> 8][idx & 255] = ne[(size_t)row0 * HID + idx];
    if (tid < RPB) {
        int b = (int)log1pf((float)degs[row0 + tid]);
        bin_s[tid] = b < 0 ? 0 : (b > 99 ? 99 : b);
    }
    __syncthreads();
    int j = tid;
    float acc[RPB];
#pragma unroll
    for (int r = 0; r < RPB; ++r)
        acc[r] = bvec[j] + dtab[bin_s[r] * HID + j];
    for (int k = 0; k < HID; k += 4) {
        float w0 = W[(k + 0) * HID + j], w1 = W[(k + 1) * HID + j];
        float w2 = W[(k + 2) * HID + j], w3 = W[(k + 3) * HID + j];
#pragma unroll
        for (int r = 0; r < RPB; ++r) {
            float4 av = *(const float4*)&a_s[r][k];
            acc[r] = fmaf(av.x, w0, fmaf(av.y, w1, fmaf(av.z, w2, fmaf(av.w, w3, acc[r]))));
        }
    }
#pragma unroll
    for (int r = 0; r < RPB; ++r)
        z[(size_t)(row0 + r) * HID + j] = acc[r];
}

// h = z @ conv_W[l]   (fp32)
__global__ __launch_bounds__(256) void gemm_conv_k(const float* __restrict__ zin,
        const float* __restrict__ W, float* __restrict__ hout) {
    __shared__ __align__(16) float a_s[RPB][HID];
    int tid = threadIdx.x;
    int row0 = blockIdx.x * RPB;
    for (int idx = tid; idx < RPB * HID; idx += 256)
        a_s[idx >> 8][idx & 255] = zin[(size_t)row0 * HID + idx];
    __syncthreads();
    int j = tid;
    float acc[RPB];
#pragma unroll
    for (int r = 0; r < RPB; ++r) acc[r] = 0.f;
    for (int k = 0; k < HID; k += 4) {
        float w0 = W[(k + 0) * HID + j], w1 = W[(k + 1) * HID + j];
        float w2 = W[(k + 2) * HID + j], w3 = W[(k + 3) * HID + j];
#pragma unroll
        for (int r = 0; r < RPB; ++r) {
            float4 av = *(const float4*)&a_s[r][k];
            acc[r] = fmaf(av.x, w0, fmaf(av.y, w1, fmaf(av.z, w2, fmaf(av.w, w3, acc[r]))));
        }
    }
#pragma unroll
    for (int r = 0; r < RPB; ++r)
        hout[(size_t)(row0 + r) * HID + j] = acc[r];
}

// CSR gather: z[c] = relu( sum_{e in bucket(c)} h[src_e]*norm_e + bias )
__global__ __launch_bounds__(256) void agg_k(const int* __restrict__ offs,
        const int* __restrict__ csr_src, const float* __restrict__ csr_norm,
        const float* __restrict__ h, const float* __restrict__ bias,
        float* __restrict__ z) {
    int node = blockIdx.x * 4 + (threadIdx.x >> 6);
    int lane = threadIdx.x & 63;
    int s = offs[node], e = offs[node + 1];
    float4 acc = make_float4(0.f, 0.f, 0.f, 0.f);
    for (int i = s; i < e; ++i) {
        int r = csr_src[i];
        float nv = csr_norm[i];
        float4 hv = *(const float4*)&h[(size_t)r * HID + lane * 4];
        acc.x = fmaf(hv.x, nv, acc.x);
        acc.y = fmaf(hv.y, nv, acc.y);
        acc.z = fmaf(hv.z, nv, acc.z);
        acc.w = fmaf(hv.w, nv, acc.w);
    }
    float4 bv = *(const float4*)&bias[lane * 4];
    acc.x = fmaxf(acc.x + bv.x, 0.f);
    acc.y = fmaxf(acc.y + bv.y, 0.f);
    acc.z = fmaxf(acc.z + bv.z, 0.f);
    acc.w = fmaxf(acc.w + bv.w, 0.f);
    *(float4*)&z[(size_t)node * HID + lane * 4] = acc;
}

// MFMA decoder: 16 edges/block, 4 waves; W1 (K=256) + W2 (K=256) on matrix cores.
// Fragment maps (m89-verified): A row=ln, k=lg*8+j; B col=ln, k=lg*8+j; D col=ln, row=lg*4+r.
__global__ __launch_bounds__(256) void decode_mfma_k(const float* __restrict__ z,
        const int* __restrict__ edges, const int* __restrict__ heur,
        const float* __restrict__ htab,
        const unsigned short* __restrict__ W1T, const float* __restrict__ b1,
        const unsigned short* __restrict__ W2T, const float* __restrict__ b2,
        const float* __restrict__ W3, const float* __restrict__ b3,
        float* __restrict__ out) {
    __shared__ __align__(16) unsigned short s_s[16][SPAD];
    __shared__ __align__(16) unsigned short x1_s[16][SPAD];
    __shared__ __align__(16) float x2_s[16][68];   // 68: +4 words/row kills W3 bank serialization
    __shared__ int hv_s[16][4];
    int tid = threadIdx.x;
    int e0 = blockIdx.x * 16;
    // stage structural products as bf16
    for (int idx = tid; idx < 16 * 256; idx += 256) {
        int e = idx >> 8, k = idx & 255;
        int a = edges[(e0 + e) * 2], b = edges[(e0 + e) * 2 + 1];
        s_s[e][k] = f2bf(z[(size_t)a * HID + k] * z[(size_t)b * HID + k]);
    }
    if (tid < 64) hv_s[tid >> 2][tid & 3] = heur[(e0 + (tid >> 2)) * 4 + (tid & 3)];
    __syncthreads();

    int lane = tid & 63, wave = tid >> 6;
    int lg = lane >> 4, ln = lane & 15;
    int n0 = wave * 64;

    // ---- W1: each wave owns 64 cols = 4 n-frags ----
    f32x4 acc[4];
#pragma unroll
    for (int f = 0; f < 4; ++f) acc[f] = (f32x4){0.f, 0.f, 0.f, 0.f};
#pragma unroll
    for (int ks = 0; ks < 8; ++ks) {
        bf16x8 af = *(const bf16x8*)&s_s[ln][ks * 32 + lg * 8];
#pragma unroll
        for (int f = 0; f < 4; ++f) {
            int n = n0 + f * 16 + ln;
            bf16x8 bv = *(const bf16x8*)&W1T[n * 256 + ks * 32 + lg * 8];
            acc[f] = __builtin_amdgcn_mfma_f32_16x16x32_bf16(af, bv, acc[f], 0, 0, 0);
        }
    }
    // epilogue: + b1 + folded heuristic tables, relu, -> x1 bf16
#pragma unroll
    for (int f = 0; f < 4; ++f) {
        int n = n0 + f * 16 + ln;
        float bcol = b1[n];
#pragma unroll
        for (int r = 0; r < 4; ++r) {
            int m = lg * 4 + r;
            float bias = bcol
                + htab[(0 * 100 + hv_s[m][0]) * HID + n]
                + htab[(1 * 100 + hv_s[m][1]) * HID + n]
                + htab[(2 * 100 + hv_s[m][2]) * HID + n]
                + htab[(3 * 100 + hv_s[m][3]) * HID + n];
            x1_s[m][n] = f2bf(fmaxf(acc[f][r] + bias, 0.f));
        }
    }
    __syncthreads();

    // ---- W2: each wave owns 16 of the 64 cols ----
    float bb = b2[wave * 16 + ln];
    f32x4 acc2 = (f32x4){bb, bb, bb, bb};
#pragma unroll
    for (int ks = 0; ks < 8; ++ks) {
        bf16x8 af = *(const bf16x8*)&x1_s[ln][ks * 32 + lg * 8];
        bf16x8 bv = *(const bf16x8*)&W2T[(wave * 16 + ln) * 256 + ks * 32 + lg * 8];
        acc2 = __builtin_amdgcn_mfma_f32_16x16x32_bf16(af, bv, acc2, 0, 0, 0);
    }
#pragma unroll
    for (int r = 0; r < 4; ++r)
        x2_s[lg * 4 + r][wave * 16 + ln] = fmaxf(acc2[r], 0.f);
    __syncthreads();

    // ---- W3: 64-dot per edge, fp32 ----
    if (tid < 16) {
        float a3 = b3[0];
#pragma unroll
        for (int k = 0; k < 64; ++k) a3 = fmaf(x2_s[tid][k], W3[k], a3);
        out[e0 + tid] = a3;
    }
}

extern "C" void kernel_launch(void* const* d_in, const int* in_sizes, int n_in,
                              void* d_out, int out_size, void* d_ws, size_t ws_size,
                              hipStream_t stream) {
    (void)in_sizes; (void)n_in; (void)out_size; (void)ws_size;
    const int*   edge_index = (const int*)d_in[0];
    const int*   pos_edge   = (const int*)d_in[1];
    const int*   neg_edge   = (const int*)d_in[2];
    const int*   pos_h      = (const int*)d_in[3];
    const int*   neg_h      = (const int*)d_in[4];
    const int*   degrees    = (const int*)d_in[5];
    const float* node_emb   = (const float*)d_in[6];
    const float* degree_emb = (const float*)d_in[7];
    const float* proj_W     = (const float*)d_in[8];
    const float* proj_b     = (const float*)d_in[9];
    const float* conv_W     = (const float*)d_in[10];
    const float* conv_b     = (const float*)d_in[11];
    const float* heur_emb   = (const float*)d_in[12];
    const float* W1         = (const float*)d_in[13];
    const float* b1         = (const float*)d_in[14];
    const float* W2         = (const float*)d_in[15];
    const float* b2         = (const float*)d_in[16];
    const float* W3         = (const float*)d_in[17];
    const float* b3         = (const float*)d_in[18];
    float* out = (float*)d_out;
    float* ws  = (float*)d_ws;

    float* z        = ws + OFF_Z;
    float* h        = ws + OFF_H;
    int*   deg      = (int*)(ws + OFF_DEG);
    float* dinv     = ws + OFF_DINV;
    float* dtab     = ws + OFF_DTAB;
    float* htab     = ws + OFF_HTAB;
    int*   offs     = (int*)(ws + OFF_OFFS);
    int*   bsum     = (int*)(ws + OFF_BSUM);
    int*   cursor   = (int*)(ws + OFF_CURS);
    int*   csr_src  = (int*)(ws + OFF_CSRC);
    float* csr_norm = ws + OFF_CNRM;
    unsigned short* W1T = (unsigned short*)(ws + OFF_W1T);
    unsigned short* W2T = (unsigned short*)(ws + OFF_W2T);

    hipMemsetAsync(deg, 0, N_NODES * sizeof(int), stream);
    count_deg_k<<<(E_GRAPH + 255) / 256, 256, 0, stream>>>(edge_index + E_GRAPH, deg);
    dinv_k<<<(N_NODES + 255) / 256, 256, 0, stream>>>(deg, dinv);

    // CSR (by destination), built once
    scan_block_k<<<NB_SCAN, 256, 0, stream>>>(deg, offs, bsum);
    scan_bsum_k<<<1, 512, 0, stream>>>(bsum, offs);
    add_bsum_k<<<NB_SCAN, 256, 0, stream>>>(offs, bsum, cursor);
    bucket_k<<<(E_GRAPH + 255) / 256, 256, 0, stream>>>(edge_index, dinv, cursor,
                                                        csr_src, csr_norm);

    dtab_k<<<100, 256, 0, stream>>>(degree_emb, proj_W, dtab);
    htab_k<<<400, 256, 0, stream>>>(heur_emb, W1, htab);
    w1t_k<<<256, 256, 0, stream>>>(W1, W1T);
    w2t_k<<<64, 256, 0, stream>>>(W2, W2T);

    proj_k<<<N_NODES / RPB, 256, 0, stream>>>(node_emb, proj_W, proj_b, dtab, degrees, z);

    for (int l = 0; l < 2; ++l) {
        gemm_conv_k<<<N_NODES / RPB, 256, 0, stream>>>(z, conv_W + l * HID * HID, h);
        agg_k<<<N_NODES / 4, 256, 0, stream>>>(offs, csr_src, csr_norm, h,
                                               conv_b + l * HID, z);
    }

    decode_mfma_k<<<E_CAND / 16, 256, 0, stream>>>(z, pos_edge, pos_h, htab,
                                                   W1T, b1, W2T, b2, W3, b3, out);
    decode_mfma_k<<<E_CAND / 16, 256, 0, stream>>>(z, neg_edge, neg_h, htab,
                                                   W1T, b1, W2T, b2, W3, b3, out + E_CAND);
}

// Round 6
// 1150.302 us; speedup vs baseline: 3.6775x; 1.4436x over previous
//
#include <hip/hip_runtime.h>
#include <hip/hip_bf16.h>

#define N_NODES 100000
#define E_GRAPH 300000
#define E_CAND  200000
#define HID     256
#define MT      64   // rows per block in MFMA node GEMMs
#define GN      ((N_NODES + MT - 1) / MT)   // 1563
#define NB_SCAN ((N_NODES + 255) / 256)     // 391
#define SPAD    264  // padded bf16 LDS row (528 B -> 4-bank shift/row, 2-way = free)

typedef __attribute__((ext_vector_type(8))) short bf16x8;
typedef __attribute__((ext_vector_type(4))) float f32x4;

// ---------------- workspace layout (float units) ----------------
static const size_t OFF_Z    = 0;
static const size_t OFF_H    = (size_t)N_NODES * HID;
static const size_t OFF_DEG  = 2 * (size_t)N_NODES * HID;          // N ints
static const size_t OFF_DINV = OFF_DEG + N_NODES;                  // N floats
static const size_t OFF_DTAB = OFF_DINV + N_NODES;                 // 100*HID
static const size_t OFF_HTAB = OFF_DTAB + 100 * HID;               // 4*100*HID
static const size_t OFF_OFFS = OFF_HTAB + 4 * 100 * HID;           // N+1 ints
static const size_t OFF_BSUM = OFF_OFFS + N_NODES + 1;             // 512 ints
static const size_t OFF_CURS = OFF_BSUM + 512;                     // N ints
static const size_t OFF_CSRC = OFF_CURS + N_NODES;                 // E ints
static const size_t OFF_CNRM = OFF_CSRC + E_GRAPH;                 // E floats
static const size_t OFF_W1T  = OFF_CNRM + E_GRAPH;                 // 256x256 bf16 = 32768 f
static const size_t OFF_W2T  = OFF_W1T + 32768;                    // 64x256 bf16  = 8192 f
static const size_t OFF_PWT  = OFF_W2T + 8192;                     // 256x256 bf16 = 32768 f
static const size_t OFF_CWT  = OFF_PWT + 32768;                    // 2x256x256 bf16 = 65536 f

__device__ inline unsigned short f2bf(float f) {
    __hip_bfloat16 h = __float2bfloat16(f);
    return *reinterpret_cast<unsigned short*>(&h);
}

__global__ void count_deg_k(const int* __restrict__ col, int* __restrict__ deg) {
    int i = blockIdx.x * 256 + threadIdx.x;
    if (i < E_GRAPH) atomicAdd(&deg[col[i]], 1);
}

__global__ void dinv_k(const int* __restrict__ deg, float* __restrict__ dinv) {
    int i = blockIdx.x * 256 + threadIdx.x;
    if (i < N_NODES) {
        int d = deg[i];
        dinv[i] = d > 0 ? 1.0f / sqrtf((float)d) : 0.0f;
    }
}

// ---- 3-kernel exclusive scan of deg -> offs ----
__global__ void scan_block_k(const int* __restrict__ deg, int* __restrict__ offs,
                             int* __restrict__ bsum) {
    __shared__ int s[256];
    int tid = threadIdx.x, i = blockIdx.x * 256 + tid;
    int v = (i < N_NODES) ? deg[i] : 0;
    s[tid] = v;
    __syncthreads();
    for (int off = 1; off < 256; off <<= 1) {
        int t = (tid >= off) ? s[tid - off] : 0;
        __syncthreads();
        s[tid] += t;
        __syncthreads();
    }
    if (i < N_NODES) offs[i] = s[tid] - v;
    if (tid == 255) bsum[blockIdx.x] = s[255];
}

__global__ void scan_bsum_k(int* __restrict__ bsum, int* __restrict__ offs) {
    __shared__ int s[512];
    int tid = threadIdx.x;
    int v = (tid < NB_SCAN) ? bsum[tid] : 0;
    s[tid] = v;
    __syncthreads();
    for (int off = 1; off < 512; off <<= 1) {
        int t = (tid >= off) ? s[tid - off] : 0;
        __syncthreads();
        s[tid] += t;
        __syncthreads();
    }
    if (tid < NB_SCAN) bsum[tid] = s[tid] - v;
    if (tid == 0) offs[N_NODES] = E_GRAPH;
}

__global__ void add_bsum_k(int* __restrict__ offs, const int* __restrict__ bsum,
                           int* __restrict__ cursor) {
    int i = blockIdx.x * 256 + threadIdx.x;
    if (i < N_NODES) {
        int o = offs[i] + bsum[i >> 8];
        offs[i] = o;
        cursor[i] = o;
    }
}

__global__ void bucket_k(const int* __restrict__ ei, const float* __restrict__ dinv,
                         int* __restrict__ cursor, int* __restrict__ csr_src,
                         float* __restrict__ csr_norm) {
    int e = blockIdx.x * 256 + threadIdx.x;
    if (e < E_GRAPH) {
        int r = ei[e], c = ei[E_GRAPH + e];
        int pos = atomicAdd(&cursor[c], 1);
        csr_src[pos] = r;
        csr_norm[pos] = dinv[r] * dinv[c];
    }
}

__global__ void dtab_k(const float* __restrict__ demb, const float* __restrict__ projW,
                       float* __restrict__ dtab) {
    int b = blockIdx.x, j = threadIdx.x;
    float acc = 0.f;
#pragma unroll
    for (int t = 0; t < 16; ++t)
        acc = fmaf(demb[b * 16 + t], projW[(256 + t) * HID + j], acc);
    dtab[b * HID + j] = acc;
}

__global__ void htab_k(const float* __restrict__ hemb, const float* __restrict__ W1,
                       float* __restrict__ htab) {
    int b = blockIdx.x;           // i*100 + v
    int i = b / 100, j = threadIdx.x;
    float acc = 0.f;
#pragma unroll
    for (int t = 0; t < 16; ++t)
        acc = fmaf(hemb[b * 16 + t], W1[(256 + i * 16 + t) * HID + j], acc);
    htab[b * HID + j] = acc;
}

// transpose+cast src[k][n] (leading dim ld) -> dst[n][k] bf16, K=256 per row
__global__ void wt_k(const float* __restrict__ src, unsigned short* __restrict__ dst,
                     int ld) {
    int n = blockIdx.x, k = threadIdx.x;
    dst[n * 256 + k] = f2bf(src[k * ld + n]);
}

// ---- MFMA node GEMMs: 64 rows x 256 cols per block, 4 waves ----
// Fragment maps (m89-verified): A row=ln, k=lg*8+j; B col(n)=ln, k=lg*8+j; D col=ln, row=lg*4+r.

// h = z @ conv_W[l]  (bf16 MFMA, fp32 accum)
__global__ __launch_bounds__(256) void conv_mfma_k(const float* __restrict__ zin,
        const unsigned short* __restrict__ WT, float* __restrict__ hout) {
    __shared__ __align__(16) unsigned short s_a[MT][SPAD];
    int tid = threadIdx.x;
    int row0 = blockIdx.x * MT;
    for (int i = tid; i < MT * 64; i += 256) {
        int r = i >> 6, c4 = (i & 63) * 4;
        int grow = row0 + r;
        float4 v = (grow < N_NODES) ? *(const float4*)&zin[(size_t)grow * HID + c4]
                                    : make_float4(0.f, 0.f, 0.f, 0.f);
        ushort4 u = { f2bf(v.x), f2bf(v.y), f2bf(v.z), f2bf(v.w) };
        *(ushort4*)&s_a[r][c4] = u;
    }
    __syncthreads();
    int lane = tid & 63, wave = tid >> 6;
    int lg = lane >> 4, ln = lane & 15, n0 = wave * 64;
    f32x4 acc[4][4];
#pragma unroll
    for (int mt = 0; mt < 4; ++mt)
#pragma unroll
        for (int f = 0; f < 4; ++f) acc[mt][f] = (f32x4){0.f, 0.f, 0.f, 0.f};
#pragma unroll
    for (int ks = 0; ks < 8; ++ks) {
        bf16x8 bv[4];
#pragma unroll
        for (int f = 0; f < 4; ++f)
            bv[f] = *(const bf16x8*)&WT[(n0 + f * 16 + ln) * 256 + ks * 32 + lg * 8];
#pragma unroll
        for (int mt = 0; mt < 4; ++mt) {
            bf16x8 af = *(const bf16x8*)&s_a[mt * 16 + ln][ks * 32 + lg * 8];
#pragma unroll
            for (int f = 0; f < 4; ++f)
                acc[mt][f] = __builtin_amdgcn_mfma_f32_16x16x32_bf16(af, bv[f], acc[mt][f], 0, 0, 0);
        }
    }
#pragma unroll
    for (int mt = 0; mt < 4; ++mt)
#pragma unroll
        for (int f = 0; f < 4; ++f)
#pragma unroll
            for (int r = 0; r < 4; ++r) {
                int row = row0 + mt * 16 + lg * 4 + r;
                if (row < N_NODES)
                    hout[(size_t)row * HID + n0 + f * 16 + ln] = acc[mt][f][r];
            }
}

// z = node_emb @ proj_W[0:256] + dtab[bin] + proj_b  (bf16 MFMA, fp32 epilogue)
__global__ __launch_bounds__(256) void proj_mfma_k(const float* __restrict__ ne,
        const unsigned short* __restrict__ PWT, const float* __restrict__ bvec,
        const float* __restrict__ dtab, const int* __restrict__ degs,
        float* __restrict__ z) {
    __shared__ __align__(16) unsigned short s_a[MT][SPAD];
    __shared__ int bin_s[MT];
    int tid = threadIdx.x;
    int row0 = blockIdx.x * MT;
    for (int i = tid; i < MT * 64; i += 256) {
        int r = i >> 6, c4 = (i & 63) * 4;
        int grow = row0 + r;
        float4 v = (grow < N_NODES) ? *(const float4*)&ne[(size_t)grow * HID + c4]
                                    : make_float4(0.f, 0.f, 0.f, 0.f);
        ushort4 u = { f2bf(v.x), f2bf(v.y), f2bf(v.z), f2bf(v.w) };
        *(ushort4*)&s_a[r][c4] = u;
    }
    if (tid < MT) {
        int grow = row0 + tid;
        int b = (grow < N_NODES) ? (int)log1pf((float)degs[grow]) : 0;
        bin_s[tid] = b < 0 ? 0 : (b > 99 ? 99 : b);
    }
    __syncthreads();
    int lane = tid & 63, wave = tid >> 6;
    int lg = lane >> 4, ln = lane & 15, n0 = wave * 64;
    f32x4 acc[4][4];
#pragma unroll
    for (int mt = 0; mt < 4; ++mt)
#pragma unroll
        for (int f = 0; f < 4; ++f) acc[mt][f] = (f32x4){0.f, 0.f, 0.f, 0.f};
#pragma unroll
    for (int ks = 0; ks < 8; ++ks) {
        bf16x8 bv[4];
#pragma unroll
        for (int f = 0; f < 4; ++f)
            bv[f] = *(const bf16x8*)&PWT[(n0 + f * 16 + ln) * 256 + ks * 32 + lg * 8];
#pragma unroll
        for (int mt = 0; mt < 4; ++mt) {
            bf16x8 af = *(const bf16x8*)&s_a[mt * 16 + ln][ks * 32 + lg * 8];
#pragma unroll
            for (int f = 0; f < 4; ++f)
                acc[mt][f] = __builtin_amdgcn_mfma_f32_16x16x32_bf16(af, bv[f], acc[mt][f], 0, 0, 0);
        }
    }
#pragma unroll
    for (int mt = 0; mt < 4; ++mt)
#pragma unroll
        for (int f = 0; f < 4; ++f) {
            int n = n0 + f * 16 + ln;
            float bc = bvec[n];
#pragma unroll
            for (int r = 0; r < 4; ++r) {
                int rl = mt * 16 + lg * 4 + r;
                int row = row0 + rl;
                if (row < N_NODES)
                    z[(size_t)row * HID + n] = acc[mt][f][r] + bc + dtab[bin_s[rl] * HID + n];
            }
        }
}

// CSR gather: z[c] = relu( sum_{e in bucket(c)} h[src_e]*norm_e + bias )
__global__ __launch_bounds__(256) void agg_k(const int* __restrict__ offs,
        const int* __restrict__ csr_src, const float* __restrict__ csr_norm,
        const float* __restrict__ h, const float* __restrict__ bias,
        float* __restrict__ z) {
    int node = blockIdx.x * 4 + (threadIdx.x >> 6);
    int lane = threadIdx.x & 63;
    int s = offs[node], e = offs[node + 1];
    float4 acc = make_float4(0.f, 0.f, 0.f, 0.f);
    for (int i = s; i < e; ++i) {
        int r = csr_src[i];
        float nv = csr_norm[i];
        float4 hv = *(const float4*)&h[(size_t)r * HID + lane * 4];
        acc.x = fmaf(hv.x, nv, acc.x);
        acc.y = fmaf(hv.y, nv, acc.y);
        acc.z = fmaf(hv.z, nv, acc.z);
        acc.w = fmaf(hv.w, nv, acc.w);
    }
    float4 bv = *(const float4*)&bias[lane * 4];
    acc.x = fmaxf(acc.x + bv.x, 0.f);
    acc.y = fmaxf(acc.y + bv.y, 0.f);
    acc.z = fmaxf(acc.z + bv.z, 0.f);
    acc.w = fmaxf(acc.w + bv.w, 0.f);
    *(float4*)&z[(size_t)node * HID + lane * 4] = acc;
}

// MFMA decoder (unchanged from R3): 16 edges/block, 4 waves.
__global__ __launch_bounds__(256) void decode_mfma_k(const float* __restrict__ z,
        const int* __restrict__ edges, const int* __restrict__ heur,
        const float* __restrict__ htab,
        const unsigned short* __restrict__ W1T, const float* __restrict__ b1,
        const unsigned short* __restrict__ W2T, const float* __restrict__ b2,
        const float* __restrict__ W3, const float* __restrict__ b3,
        float* __restrict__ out) {
    __shared__ __align__(16) unsigned short s_s[16][SPAD];
    __shared__ __align__(16) unsigned short x1_s[16][SPAD];
    __shared__ __align__(16) float x2_s[16][68];
    __shared__ int hv_s[16][4];
    int tid = threadIdx.x;
    int e0 = blockIdx.x * 16;
    for (int idx = tid; idx < 16 * 256; idx += 256) {
        int e = idx >> 8, k = idx & 255;
        int a = edges[(e0 + e) * 2], b = edges[(e0 + e) * 2 + 1];
        s_s[e][k] = f2bf(z[(size_t)a * HID + k] * z[(size_t)b * HID + k]);
    }
    if (tid < 64) hv_s[tid >> 2][tid & 3] = heur[(e0 + (tid >> 2)) * 4 + (tid & 3)];
    __syncthreads();

    int lane = tid & 63, wave = tid >> 6;
    int lg = lane >> 4, ln = lane & 15;
    int n0 = wave * 64;

    f32x4 acc[4];
#pragma unroll
    for (int f = 0; f < 4; ++f) acc[f] = (f32x4){0.f, 0.f, 0.f, 0.f};
#pragma unroll
    for (int ks = 0; ks < 8; ++ks) {
        bf16x8 af = *(const bf16x8*)&s_s[ln][ks * 32 + lg * 8];
#pragma unroll
        for (int f = 0; f < 4; ++f) {
            int n = n0 + f * 16 + ln;
            bf16x8 bv = *(const bf16x8*)&W1T[n * 256 + ks * 32 + lg * 8];
            acc[f] = __builtin_amdgcn_mfma_f32_16x16x32_bf16(af, bv, acc[f], 0, 0, 0);
        }
    }
#pragma unroll
    for (int f = 0; f < 4; ++f) {
        int n = n0 + f * 16 + ln;
        float bcol = b1[n];
#pragma unroll
        for (int r = 0; r < 4; ++r) {
            int m = lg * 4 + r;
            float bias = bcol
                + htab[(0 * 100 + hv_s[m][0]) * HID + n]
                + htab[(1 * 100 + hv_s[m][1]) * HID + n]
                + htab[(2 * 100 + hv_s[m][2]) * HID + n]
                + htab[(3 * 100 + hv_s[m][3]) * HID + n];
            x1_s[m][n] = f2bf(fmaxf(acc[f][r] + bias, 0.f));
        }
    }
    __syncthreads();

    float bb = b2[wave * 16 + ln];
    f32x4 acc2 = (f32x4){bb, bb, bb, bb};
#pragma unroll
    for (int ks = 0; ks < 8; ++ks) {
        bf16x8 af = *(const bf16x8*)&x1_s[ln][ks * 32 + lg * 8];
        bf16x8 bv = *(const bf16x8*)&W2T[(wave * 16 + ln) * 256 + ks * 32 + lg * 8];
        acc2 = __builtin_amdgcn_mfma_f32_16x16x32_bf16(af, bv, acc2, 0, 0, 0);
    }
#pragma unroll
    for (int r = 0; r < 4; ++r)
        x2_s[lg * 4 + r][wave * 16 + ln] = fmaxf(acc2[r], 0.f);
    __syncthreads();

    if (tid < 16) {
        float a3 = b3[0];
#pragma unroll
        for (int k = 0; k < 64; ++k) a3 = fmaf(x2_s[tid][k], W3[k], a3);
        out[e0 + tid] = a3;
    }
}

extern "C" void kernel_launch(void* const* d_in, const int* in_sizes, int n_in,
                              void* d_out, int out_size, void* d_ws, size_t ws_size,
                              hipStream_t stream) {
    (void)in_sizes; (void)n_in; (void)out_size; (void)ws_size;
    const int*   edge_index = (const int*)d_in[0];
    const int*   pos_edge   = (const int*)d_in[1];
    const int*   neg_edge   = (const int*)d_in[2];
    const int*   pos_h      = (const int*)d_in[3];
    const int*   neg_h      = (const int*)d_in[4];
    const int*   degrees    = (const int*)d_in[5];
    const float* node_emb   = (const float*)d_in[6];
    const float* degree_emb = (const float*)d_in[7];
    const float* proj_W     = (const float*)d_in[8];
    const float* proj_b     = (const float*)d_in[9];
    const float* conv_W     = (const float*)d_in[10];
    const float* conv_b     = (const float*)d_in[11];
    const float* heur_emb   = (const float*)d_in[12];
    const float* W1         = (const float*)d_in[13];
    const float* b1         = (const float*)d_in[14];
    const float* W2         = (const float*)d_in[15];
    const float* b2         = (const float*)d_in[16];
    const float* W3         = (const float*)d_in[17];
    const float* b3         = (const float*)d_in[18];
    float* out = (float*)d_out;
    float* ws  = (float*)d_ws;

    float* z        = ws + OFF_Z;
    float* h        = ws + OFF_H;
    int*   deg      = (int*)(ws + OFF_DEG);
    float* dinv     = ws + OFF_DINV;
    float* dtab     = ws + OFF_DTAB;
    float* htab     = ws + OFF_HTAB;
    int*   offs     = (int*)(ws + OFF_OFFS);
    int*   bsum     = (int*)(ws + OFF_BSUM);
    int*   cursor   = (int*)(ws + OFF_CURS);
    int*   csr_src  = (int*)(ws + OFF_CSRC);
    float* csr_norm = ws + OFF_CNRM;
    unsigned short* W1T = (unsigned short*)(ws + OFF_W1T);
    unsigned short* W2T = (unsigned short*)(ws + OFF_W2T);
    unsigned short* PWT = (unsigned short*)(ws + OFF_PWT);
    unsigned short* CWT = (unsigned short*)(ws + OFF_CWT);

    hipMemsetAsync(deg, 0, N_NODES * sizeof(int), stream);
    count_deg_k<<<(E_GRAPH + 255) / 256, 256, 0, stream>>>(edge_index + E_GRAPH, deg);
    dinv_k<<<(N_NODES + 255) / 256, 256, 0, stream>>>(deg, dinv);

    // CSR (by destination), built once
    scan_block_k<<<NB_SCAN, 256, 0, stream>>>(deg, offs, bsum);
    scan_bsum_k<<<1, 512, 0, stream>>>(bsum, offs);
    add_bsum_k<<<NB_SCAN, 256, 0, stream>>>(offs, bsum, cursor);
    bucket_k<<<(E_GRAPH + 255) / 256, 256, 0, stream>>>(edge_index, dinv, cursor,
                                                        csr_src, csr_norm);

    dtab_k<<<100, 256, 0, stream>>>(degree_emb, proj_W, dtab);
    htab_k<<<400, 256, 0, stream>>>(heur_emb, W1, htab);
    wt_k<<<256, 256, 0, stream>>>(W1, W1T, 256);
    wt_k<<<64, 256, 0, stream>>>(W2, W2T, 64);
    wt_k<<<256, 256, 0, stream>>>(proj_W, PWT, 256);
    wt_k<<<256, 256, 0, stream>>>(conv_W, CWT, 256);
    wt_k<<<256, 256, 0, stream>>>(conv_W + 65536, CWT + 65536, 256);

    proj_mfma_k<<<GN, 256, 0, stream>>>(node_emb, PWT, proj_b, dtab, degrees, z);

    for (int l = 0; l < 2; ++l) {
        conv_mfma_k<<<GN, 256, 0, stream>>>(z, CWT + l * 65536, h);
        agg_k<<<N_NODES / 4, 256, 0, stream>>>(offs, csr_src, csr_norm, h,
                                               conv_b + l * HID, z);
    }

    decode_mfma_k<<<E_CAND / 16, 256, 0, stream>>>(z, pos_edge, pos_h, htab,
                                                   W1T, b1, W2T, b2, W3, b3, out);
    decode_mfma_k<<<E_CAND / 16, 256, 0, stream>>>(z, neg_edge, neg_h, htab,
                                                   W1T, b1, W2T, b2, W3, b3, out + E_CAND);
}

// Round 7
// 833.832 us; speedup vs baseline: 5.0733x; 1.3795x over previous
//
#include <hip/hip_runtime.h>
#include <hip/hip_bf16.h>

#define N_NODES 100000
#define E_GRAPH 300000
#define E_CAND  200000
#define HID     256
#define MT      64   // rows per block in MFMA node GEMMs
#define GN      ((N_NODES + MT - 1) / MT)   // 1563
#define NB_SCAN ((N_NODES + 255) / 256)     // 391
#define SPAD    264  // padded bf16 LDS row (528 B -> 4-bank shift/row, 2-way = free)
#define EB      32   // edges per decode block
#define NBH     (E_CAND / EB)               // 6250 blocks per pos/neg half

typedef __attribute__((ext_vector_type(8))) short bf16x8;
typedef __attribute__((ext_vector_type(8))) unsigned short u16x8;
typedef __attribute__((ext_vector_type(4))) float f32x4;

// ---------------- workspace layout (float units) ----------------
#define NH2 ((size_t)N_NODES * HID / 2)     // bf16 node-feature buffer, in floats
static const size_t OFF_ZB   = 0;                                  // N*HID bf16
static const size_t OFF_HB   = NH2;                                // N*HID bf16
static const size_t OFF_DEG  = 2 * NH2;                            // N ints
static const size_t OFF_DINV = OFF_DEG + N_NODES;                  // N floats
static const size_t OFF_DTAB = OFF_DINV + N_NODES;                 // 100*HID
static const size_t OFF_HTAB = OFF_DTAB + 100 * HID;               // 4*100*HID
static const size_t OFF_OFFS = OFF_HTAB + 4 * 100 * HID;           // N+1 ints
static const size_t OFF_BSUM = OFF_OFFS + N_NODES + 1;             // 512 ints
static const size_t OFF_CURS = OFF_BSUM + 512;                     // N ints
static const size_t OFF_CSRC = OFF_CURS + N_NODES;                 // E ints
static const size_t OFF_CNRM = OFF_CSRC + E_GRAPH;                 // E floats
static const size_t OFF_W1T  = OFF_CNRM + E_GRAPH;                 // 256x256 bf16
static const size_t OFF_W2T  = OFF_W1T + 32768;                    // 64x256 bf16
static const size_t OFF_PWT  = OFF_W2T + 8192;                     // 256x256 bf16
static const size_t OFF_CWT  = OFF_PWT + 32768;                    // 2x256x256 bf16

__device__ inline unsigned short f2bf(float f) {
    __hip_bfloat16 h = __float2bfloat16(f);
    return *reinterpret_cast<unsigned short*>(&h);
}
__device__ inline float bf2f(unsigned short u) {
    unsigned int x = ((unsigned int)u) << 16;
    return __builtin_bit_cast(float, x);
}

__global__ void count_deg_k(const int* __restrict__ col, int* __restrict__ deg) {
    int i = blockIdx.x * 256 + threadIdx.x;
    if (i < E_GRAPH) atomicAdd(&deg[col[i]], 1);
}

__global__ void dinv_k(const int* __restrict__ deg, float* __restrict__ dinv) {
    int i = blockIdx.x * 256 + threadIdx.x;
    if (i < N_NODES) {
        int d = deg[i];
        dinv[i] = d > 0 ? 1.0f / sqrtf((float)d) : 0.0f;
    }
}

// ---- 3-kernel exclusive scan of deg -> offs ----
__global__ void scan_block_k(const int* __restrict__ deg, int* __restrict__ offs,
                             int* __restrict__ bsum) {
    __shared__ int s[256];
    int tid = threadIdx.x, i = blockIdx.x * 256 + tid;
    int v = (i < N_NODES) ? deg[i] : 0;
    s[tid] = v;
    __syncthreads();
    for (int off = 1; off < 256; off <<= 1) {
        int t = (tid >= off) ? s[tid - off] : 0;
        __syncthreads();
        s[tid] += t;
        __syncthreads();
    }
    if (i < N_NODES) offs[i] = s[tid] - v;
    if (tid == 255) bsum[blockIdx.x] = s[255];
}

__global__ void scan_bsum_k(int* __restrict__ bsum, int* __restrict__ offs) {
    __shared__ int s[512];
    int tid = threadIdx.x;
    int v = (tid < NB_SCAN) ? bsum[tid] : 0;
    s[tid] = v;
    __syncthreads();
    for (int off = 1; off < 512; off <<= 1) {
        int t = (tid >= off) ? s[tid - off] : 0;
        __syncthreads();
        s[tid] += t;
        __syncthreads();
    }
    if (tid < NB_SCAN) bsum[tid] = s[tid] - v;
    if (tid == 0) offs[N_NODES] = E_GRAPH;
}

__global__ void add_bsum_k(int* __restrict__ offs, const int* __restrict__ bsum,
                           int* __restrict__ cursor) {
    int i = blockIdx.x * 256 + threadIdx.x;
    if (i < N_NODES) {
        int o = offs[i] + bsum[i >> 8];
        offs[i] = o;
        cursor[i] = o;
    }
}

__global__ void bucket_k(const int* __restrict__ ei, const float* __restrict__ dinv,
                         int* __restrict__ cursor, int* __restrict__ csr_src,
                         float* __restrict__ csr_norm) {
    int e = blockIdx.x * 256 + threadIdx.x;
    if (e < E_GRAPH) {
        int r = ei[e], c = ei[E_GRAPH + e];
        int pos = atomicAdd(&cursor[c], 1);
        csr_src[pos] = r;
        csr_norm[pos] = dinv[r] * dinv[c];
    }
}

__global__ void dtab_k(const float* __restrict__ demb, const float* __restrict__ projW,
                       float* __restrict__ dtab) {
    int b = blockIdx.x, j = threadIdx.x;
    float acc = 0.f;
#pragma unroll
    for (int t = 0; t < 16; ++t)
        acc = fmaf(demb[b * 16 + t], projW[(256 + t) * HID + j], acc);
    dtab[b * HID + j] = acc;
}

__global__ void htab_k(const float* __restrict__ hemb, const float* __restrict__ W1,
                       float* __restrict__ htab) {
    int b = blockIdx.x;           // i*100 + v
    int i = b / 100, j = threadIdx.x;
    float acc = 0.f;
#pragma unroll
    for (int t = 0; t < 16; ++t)
        acc = fmaf(hemb[b * 16 + t], W1[(256 + i * 16 + t) * HID + j], acc);
    htab[b * HID + j] = acc;
}

// transpose+cast src[k][n] (leading dim ld) -> dst[n][k] bf16, K=256 per row
__global__ void wt_k(const float* __restrict__ src, unsigned short* __restrict__ dst,
                     int ld) {
    int n = blockIdx.x, k = threadIdx.x;
    dst[n * 256 + k] = f2bf(src[k * ld + n]);
}

// ---- MFMA node GEMMs: 64 rows x 256 cols per block, 4 waves ----
// Fragment maps (m89-verified): A row=ln, k=lg*8+j; B col(n)=ln, k=lg*8+j; D col=ln, row=lg*4+r.

// hb = zb @ conv_W[l]  (bf16 in/out, fp32 accum)
__global__ __launch_bounds__(256) void conv_mfma_k(const unsigned short* __restrict__ zb,
        const unsigned short* __restrict__ WT, unsigned short* __restrict__ hb) {
    __shared__ __align__(16) unsigned short s_a[MT][SPAD];
    int tid = threadIdx.x;
    int row0 = blockIdx.x * MT;
    for (int i = tid; i < MT * 32; i += 256) {
        int r = i >> 5, c8 = (i & 31) * 8;
        int grow = row0 + r;
        u16x8 v;
        if (grow < N_NODES) v = *(const u16x8*)&zb[(size_t)grow * HID + c8];
        else v = (u16x8){0, 0, 0, 0, 0, 0, 0, 0};
        *(u16x8*)&s_a[r][c8] = v;
    }
    __syncthreads();
    int lane = tid & 63, wave = tid >> 6;
    int lg = lane >> 4, ln = lane & 15, n0 = wave * 64;
    f32x4 acc[4][4];
#pragma unroll
    for (int mt = 0; mt < 4; ++mt)
#pragma unroll
        for (int f = 0; f < 4; ++f) acc[mt][f] = (f32x4){0.f, 0.f, 0.f, 0.f};
#pragma unroll
    for (int ks = 0; ks < 8; ++ks) {
        bf16x8 bv[4];
#pragma unroll
        for (int f = 0; f < 4; ++f)
            bv[f] = *(const bf16x8*)&WT[(n0 + f * 16 + ln) * 256 + ks * 32 + lg * 8];
#pragma unroll
        for (int mt = 0; mt < 4; ++mt) {
            bf16x8 af = *(const bf16x8*)&s_a[mt * 16 + ln][ks * 32 + lg * 8];
#pragma unroll
            for (int f = 0; f < 4; ++f)
                acc[mt][f] = __builtin_amdgcn_mfma_f32_16x16x32_bf16(af, bv[f], acc[mt][f], 0, 0, 0);
        }
    }
#pragma unroll
    for (int mt = 0; mt < 4; ++mt)
#pragma unroll
        for (int f = 0; f < 4; ++f)
#pragma unroll
            for (int r = 0; r < 4; ++r) {
                int row = row0 + mt * 16 + lg * 4 + r;
                if (row < N_NODES)
                    hb[(size_t)row * HID + n0 + f * 16 + ln] = f2bf(acc[mt][f][r]);
            }
}

// zb = node_emb @ proj_W[0:256] + dtab[bin] + proj_b  (bf16 out)
__global__ __launch_bounds__(256) void proj_mfma_k(const float* __restrict__ ne,
        const unsigned short* __restrict__ PWT, const float* __restrict__ bvec,
        const float* __restrict__ dtab, const int* __restrict__ degs,
        unsigned short* __restrict__ zb) {
    __shared__ __align__(16) unsigned short s_a[MT][SPAD];
    __shared__ int bin_s[MT];
    int tid = threadIdx.x;
    int row0 = blockIdx.x * MT;
    for (int i = tid; i < MT * 64; i += 256) {
        int r = i >> 6, c4 = (i & 63) * 4;
        int grow = row0 + r;
        float4 v = (grow < N_NODES) ? *(const float4*)&ne[(size_t)grow * HID + c4]
                                    : make_float4(0.f, 0.f, 0.f, 0.f);
        ushort4 u = { f2bf(v.x), f2bf(v.y), f2bf(v.z), f2bf(v.w) };
        *(ushort4*)&s_a[r][c4] = u;
    }
    if (tid < MT) {
        int grow = row0 + tid;
        int b = (grow < N_NODES) ? (int)log1pf((float)degs[grow]) : 0;
        bin_s[tid] = b < 0 ? 0 : (b > 99 ? 99 : b);
    }
    __syncthreads();
    int lane = tid & 63, wave = tid >> 6;
    int lg = lane >> 4, ln = lane & 15, n0 = wave * 64;
    f32x4 acc[4][4];
#pragma unroll
    for (int mt = 0; mt < 4; ++mt)
#pragma unroll
        for (int f = 0; f < 4; ++f) acc[mt][f] = (f32x4){0.f, 0.f, 0.f, 0.f};
#pragma unroll
    for (int ks = 0; ks < 8; ++ks) {
        bf16x8 bv[4];
#pragma unroll
        for (int f = 0; f < 4; ++f)
            bv[f] = *(const bf16x8*)&PWT[(n0 + f * 16 + ln) * 256 + ks * 32 + lg * 8];
#pragma unroll
        for (int mt = 0; mt < 4; ++mt) {
            bf16x8 af = *(const bf16x8*)&s_a[mt * 16 + ln][ks * 32 + lg * 8];
#pragma unroll
            for (int f = 0; f < 4; ++f)
                acc[mt][f] = __builtin_amdgcn_mfma_f32_16x16x32_bf16(af, bv[f], acc[mt][f], 0, 0, 0);
        }
    }
#pragma unroll
    for (int mt = 0; mt < 4; ++mt)
#pragma unroll
        for (int f = 0; f < 4; ++f) {
            int n = n0 + f * 16 + ln;
            float bc = bvec[n];
#pragma unroll
            for (int r = 0; r < 4; ++r) {
                int rl = mt * 16 + lg * 4 + r;
                int row = row0 + rl;
                if (row < N_NODES)
                    zb[(size_t)row * HID + n] = f2bf(acc[mt][f][r] + bc + dtab[bin_s[rl] * HID + n]);
            }
        }
}

// CSR gather: zb[c] = relu( sum_{e in bucket(c)} hb[src_e]*norm_e + bias )
__global__ __launch_bounds__(256) void agg_k(const int* __restrict__ offs,
        const int* __restrict__ csr_src, const float* __restrict__ csr_norm,
        const unsigned short* __restrict__ hb, const float* __restrict__ bias,
        unsigned short* __restrict__ zb) {
    int node = blockIdx.x * 4 + (threadIdx.x >> 6);
    int lane = threadIdx.x & 63;
    int s = offs[node], e = offs[node + 1];
    float4 acc = make_float4(0.f, 0.f, 0.f, 0.f);
    for (int i = s; i < e; ++i) {
        int r = csr_src[i];
        float nv = csr_norm[i];
        ushort4 hv = *(const ushort4*)&hb[(size_t)r * HID + lane * 4];
        acc.x = fmaf(bf2f(hv.x), nv, acc.x);
        acc.y = fmaf(bf2f(hv.y), nv, acc.y);
        acc.z = fmaf(bf2f(hv.z), nv, acc.z);
        acc.w = fmaf(bf2f(hv.w), nv, acc.w);
    }
    float4 bv = *(const float4*)&bias[lane * 4];
    ushort4 o = { f2bf(fmaxf(acc.x + bv.x, 0.f)), f2bf(fmaxf(acc.y + bv.y, 0.f)),
                  f2bf(fmaxf(acc.z + bv.z, 0.f)), f2bf(fmaxf(acc.w + bv.w, 0.f)) };
    *(ushort4*)&zb[(size_t)node * HID + lane * 4] = o;
}

// MFMA decoder, merged pos+neg: 32 edges/block, 4 waves.
__global__ __launch_bounds__(256) void decode_mfma_k(const unsigned short* __restrict__ zb,
        const int* __restrict__ pos_e, const int* __restrict__ pos_hv,
        const int* __restrict__ neg_e, const int* __restrict__ neg_hv,
        const float* __restrict__ htab,
        const unsigned short* __restrict__ W1T, const float* __restrict__ b1,
        const unsigned short* __restrict__ W2T, const float* __restrict__ b2,
        const float* __restrict__ W3, const float* __restrict__ b3,
        float* __restrict__ out) {
    __shared__ __align__(16) unsigned short s_s[EB][SPAD];
    __shared__ __align__(16) unsigned short x1_s[EB][SPAD];
    __shared__ __align__(16) float x2_s[EB][68];
    __shared__ int hv_s[EB][4];
    int tid = threadIdx.x;
    int bid = blockIdx.x;
    const int* edges; const int* heur; float* o;
    if (bid < NBH) { edges = pos_e; heur = pos_hv; o = out; }
    else           { edges = neg_e; heur = neg_hv; o = out + E_CAND; bid -= NBH; }
    int e0 = bid * EB;

    int lane = tid & 63, wave = tid >> 6;
    // stage structural products: 8 edges/wave, full row per wave (512 B coalesced)
#pragma unroll
    for (int q = 0; q < 8; ++q) {
        int e = wave * 8 + q;
        int a = edges[(e0 + e) * 2], b = edges[(e0 + e) * 2 + 1];
        ushort4 ua = *(const ushort4*)&zb[(size_t)a * HID + lane * 4];
        ushort4 ub = *(const ushort4*)&zb[(size_t)b * HID + lane * 4];
        ushort4 p = { f2bf(bf2f(ua.x) * bf2f(ub.x)), f2bf(bf2f(ua.y) * bf2f(ub.y)),
                      f2bf(bf2f(ua.z) * bf2f(ub.z)), f2bf(bf2f(ua.w) * bf2f(ub.w)) };
        *(ushort4*)&s_s[e][lane * 4] = p;
    }
    if (tid < EB * 4) hv_s[tid >> 2][tid & 3] = heur[(e0 + (tid >> 2)) * 4 + (tid & 3)];
    __syncthreads();

    int lg = lane >> 4, ln = lane & 15;
    int n0 = wave * 64;

    // ---- W1: 2 m-tiles x 4 n-frags per wave ----
    f32x4 acc[2][4];
#pragma unroll
    for (int mt = 0; mt < 2; ++mt)
#pragma unroll
        for (int f = 0; f < 4; ++f) acc[mt][f] = (f32x4){0.f, 0.f, 0.f, 0.f};
#pragma unroll
    for (int ks = 0; ks < 8; ++ks) {
        bf16x8 bv[4];
#pragma unroll
        for (int f = 0; f < 4; ++f)
            bv[f] = *(const bf16x8*)&W1T[(n0 + f * 16 + ln) * 256 + ks * 32 + lg * 8];
#pragma unroll
        for (int mt = 0; mt < 2; ++mt) {
            bf16x8 af = *(const bf16x8*)&s_s[mt * 16 + ln][ks * 32 + lg * 8];
#pragma unroll
            for (int f = 0; f < 4; ++f)
                acc[mt][f] = __builtin_amdgcn_mfma_f32_16x16x32_bf16(af, bv[f], acc[mt][f], 0, 0, 0);
        }
    }
#pragma unroll
    for (int mt = 0; mt < 2; ++mt)
#pragma unroll
        for (int f = 0; f < 4; ++f) {
            int n = n0 + f * 16 + ln;
            float bcol = b1[n];
#pragma unroll
            for (int r = 0; r < 4; ++r) {
                int m = mt * 16 + lg * 4 + r;
                float bias = bcol
                    + htab[(0 * 100 + hv_s[m][0]) * HID + n]
                    + htab[(1 * 100 + hv_s[m][1]) * HID + n]
                    + htab[(2 * 100 + hv_s[m][2]) * HID + n]
                    + htab[(3 * 100 + hv_s[m][3]) * HID + n];
                x1_s[m][n] = f2bf(fmaxf(acc[mt][f][r] + bias, 0.f));
            }
        }
    __syncthreads();

    // ---- W2: each wave owns 16 of the 64 cols, both m-tiles ----
    float bb = b2[wave * 16 + ln];
    f32x4 acc2[2] = {(f32x4){bb, bb, bb, bb}, (f32x4){bb, bb, bb, bb}};
#pragma unroll
    for (int ks = 0; ks < 8; ++ks) {
        bf16x8 bv = *(const bf16x8*)&W2T[(wave * 16 + ln) * 256 + ks * 32 + lg * 8];
#pragma unroll
        for (int mt = 0; mt < 2; ++mt) {
            bf16x8 af = *(const bf16x8*)&x1_s[mt * 16 + ln][ks * 32 + lg * 8];
            acc2[mt] = __builtin_amdgcn_mfma_f32_16x16x32_bf16(af, bv, acc2[mt], 0, 0, 0);
        }
    }
#pragma unroll
    for (int mt = 0; mt < 2; ++mt)
#pragma unroll
        for (int r = 0; r < 4; ++r)
            x2_s[mt * 16 + lg * 4 + r][wave * 16 + ln] = fmaxf(acc2[mt][r], 0.f);
    __syncthreads();

    // ---- W3: 64-dot per edge, fp32 ----
    if (tid < EB) {
        float a3 = b3[0];
#pragma unroll
        for (int k = 0; k < 64; ++k) a3 = fmaf(x2_s[tid][k], W3[k], a3);
        o[e0 + tid] = a3;
    }
}

extern "C" void kernel_launch(void* const* d_in, const int* in_sizes, int n_in,
                              void* d_out, int out_size, void* d_ws, size_t ws_size,
                              hipStream_t stream) {
    (void)in_sizes; (void)n_in; (void)out_size; (void)ws_size;
    const int*   edge_index = (const int*)d_in[0];
    const int*   pos_edge   = (const int*)d_in[1];
    const int*   neg_edge   = (const int*)d_in[2];
    const int*   pos_h      = (const int*)d_in[3];
    const int*   neg_h      = (const int*)d_in[4];
    const int*   degrees    = (const int*)d_in[5];
    const float* node_emb   = (const float*)d_in[6];
    const float* degree_emb = (const float*)d_in[7];
    const float* proj_W     = (const float*)d_in[8];
    const float* proj_b     = (const float*)d_in[9];
    const float* conv_W     = (const float*)d_in[10];
    const float* conv_b     = (const float*)d_in[11];
    const float* heur_emb   = (const float*)d_in[12];
    const float* W1         = (const float*)d_in[13];
    const float* b1         = (const float*)d_in[14];
    const float* W2         = (const float*)d_in[15];
    const float* b2         = (const float*)d_in[16];
    const float* W3         = (const float*)d_in[17];
    const float* b3         = (const float*)d_in[18];
    float* out = (float*)d_out;
    float* ws  = (float*)d_ws;

    unsigned short* zb  = (unsigned short*)(ws + OFF_ZB);
    unsigned short* hb  = (unsigned short*)(ws + OFF_HB);
    int*   deg      = (int*)(ws + OFF_DEG);
    float* dinv     = ws + OFF_DINV;
    float* dtab     = ws + OFF_DTAB;
    float* htab     = ws + OFF_HTAB;
    int*   offs     = (int*)(ws + OFF_OFFS);
    int*   bsum     = (int*)(ws + OFF_BSUM);
    int*   cursor   = (int*)(ws + OFF_CURS);
    int*   csr_src  = (int*)(ws + OFF_CSRC);
    float* csr_norm = ws + OFF_CNRM;
    unsigned short* W1T = (unsigned short*)(ws + OFF_W1T);
    unsigned short* W2T = (unsigned short*)(ws + OFF_W2T);
    unsigned short* PWT = (unsigned short*)(ws + OFF_PWT);
    unsigned short* CWT = (unsigned short*)(ws + OFF_CWT);

    hipMemsetAsync(deg, 0, N_NODES * sizeof(int), stream);
    count_deg_k<<<(E_GRAPH + 255) / 256, 256, 0, stream>>>(edge_index + E_GRAPH, deg);
    dinv_k<<<(N_NODES + 255) / 256, 256, 0, stream>>>(deg, dinv);

    // CSR (by destination), built once
    scan_block_k<<<NB_SCAN, 256, 0, stream>>>(deg, offs, bsum);
    scan_bsum_k<<<1, 512, 0, stream>>>(bsum, offs);
    add_bsum_k<<<NB_SCAN, 256, 0, stream>>>(offs, bsum, cursor);
    bucket_k<<<(E_GRAPH + 255) / 256, 256, 0, stream>>>(edge_index, dinv, cursor,
                                                        csr_src, csr_norm);

    dtab_k<<<100, 256, 0, stream>>>(degree_emb, proj_W, dtab);
    htab_k<<<400, 256, 0, stream>>>(heur_emb, W1, htab);
    wt_k<<<256, 256, 0, stream>>>(W1, W1T, 256);
    wt_k<<<64, 256, 0, stream>>>(W2, W2T, 64);
    wt_k<<<256, 256, 0, stream>>>(proj_W, PWT, 256);
    wt_k<<<256, 256, 0, stream>>>(conv_W, CWT, 256);
    wt_k<<<256, 256, 0, stream>>>(conv_W + 65536, CWT + 65536, 256);

    proj_mfma_k<<<GN, 256, 0, stream>>>(node_emb, PWT, proj_b, dtab, degrees, zb);

    for (int l = 0; l < 2; ++l) {
        conv_mfma_k<<<GN, 256, 0, stream>>>(zb, CWT + l * 65536, hb);
        agg_k<<<N_NODES / 4, 256, 0, stream>>>(offs, csr_src, csr_norm, hb,
                                               conv_b + l * HID, zb);
    }

    decode_mfma_k<<<2 * NBH, 256, 0, stream>>>(zb, pos_edge, pos_h, neg_edge, neg_h,
                                               htab, W1T, b1, W2T, b2, W3, b3, out);
}